// Round 11
// baseline (80.783 us; speedup 1.0000x reference)
//
#include <hip/hip_runtime.h>

// out[n,k] = sum_{i,j} x[n,i] * W[k,i,j] * x[n,j]   (N=262144 rows, D=32)
// R11: SYMMETRIZED GEMM. out depends only on Sym(W_k), so fold W into
// circular diagonals: p = d*32 + i (d=0..16), z[n,p] = x[n,i]*x[n,(i+d)&31],
// Wf[p,k] = W[k,i,j]+W[k,j,i] (j=(i+d)&31; d=0: W[k,i,i]; d=16: i<16 only).
// Each unordered (i,j) pair counted exactly once -> K = 528 = 33 MFMA steps
// of v_mfma_f32_32x32x16_f16 (vs 64 before: -48% MFMA, -48% ds_read, and the
// A-fragment build loses the splat: both operands are packed f16 pairs).
//   slot (hi,b) of step s: m = q*16+hi*8+b, a = x_m * x_{(m+d)&31}
//   pair t: ypk[q8+t] * (d odd ? ysh : ypk)[(q8+t+(d>>1))&15]   (all static)
// ypk/ysh = packed row / odd-shifted row, pre-rotated by hi*4 so loop
// indices are compile-time (no dynamic reg indexing). All prior falsified
// levers (coalescing, LDS-vs-L2, I$, pipelining) left at R4 structure.

typedef _Float16 f16x2 __attribute__((ext_vector_type(2)));
typedef _Float16 f16x4 __attribute__((ext_vector_type(4)));
typedef _Float16 f16x8 __attribute__((ext_vector_type(8)));
typedef float    f32x16 __attribute__((ext_vector_type(16)));

static __device__ __forceinline__ unsigned int pk2_f16(float lo, float hi) {
    return __builtin_bit_cast(unsigned int, __builtin_amdgcn_cvt_pkrtz(lo, hi));
}
static __device__ __forceinline__ f16x2 u2h(unsigned int u) {
    return __builtin_bit_cast(f16x2, u);
}
static __device__ __forceinline__ unsigned short f16b(float f) {
    _Float16 h = (_Float16)f;
    return __builtin_bit_cast(unsigned short, h);
}

__global__ __launch_bounds__(512, 4)
void quadform_kernel(const float* __restrict__ x,
                     const float* __restrict__ W,
                     float* __restrict__ out) {
    // btab[(s*64 + l)*8 + b] = f16 of Wf[16s + (l>>5)*8 + b][l&31], s=0..32
    __shared__ __align__(16) unsigned short btab[33 * 64 * 8];   // 33 KiB

    const int tid  = threadIdx.x;
    const int lane = tid & 63;
    const int wave = tid >> 6;
    const int hi   = lane >> 5;
    const int rl   = lane & 31;
    const long rowbase = (long)blockIdx.x * 512 + wave * 64;

    // ---- build symmetrized B-table: gather W[k,i,j]+W[k,j,i] ----
    {
        const int bl   = tid >> 3;           // fragment lane 0..63
        const int bb   = tid & 7;            // fragment slot 0..7
        const int bk   = bl & 31;            // output col k
        const int bhi8 = (bl >> 5) << 3;
        const float* Wk = W + bk * 1024;
        #pragma unroll
        for (int n = 0; n < 33; ++n) {
            const int d = (n == 32) ? 16 : (n >> 1);
            const int q = (n == 32) ? 0  : (n & 1);
            int i = q * 16 + bhi8 + bb;
            int j = (i + d) & 31;
            float v;
            if (d == 0) v = Wk[i * 32 + i];
            else        v = Wk[i * 32 + j] + Wk[j * 32 + i];
            btab[(n * 64 + bl) * 8 + bb] = f16b(v);
        }
    }

    // ---- tile 0: load + pack + shifted + hi-rotate ----
    unsigned int ypk0[16], ysh0[16], ypk1[16], ysh1[16];
    {
        unsigned int xpk[16], xsh[16];
        const float4* xr = (const float4*)(x + (rowbase + rl) * 32);
        #pragma unroll
        for (int c = 0; c < 8; ++c) {
            float4 v = xr[c];
            xpk[2 * c + 0] = pk2_f16(v.x, v.y);
            xpk[2 * c + 1] = pk2_f16(v.z, v.w);
        }
        #pragma unroll
        for (int c = 0; c < 16; ++c)    // (x[2c+1], x[(2c+2)&31])
            xsh[c] = __builtin_amdgcn_perm(xpk[(c + 1) & 15], xpk[c], 0x05040302u);
        #pragma unroll
        for (int c = 0; c < 16; ++c) {  // rotate by hi*4 pairs
            ypk0[c] = hi ? xpk[(c + 4) & 15] : xpk[c];
            ysh0[c] = hi ? xsh[(c + 4) & 15] : xsh[c];
        }
    }
    // ---- tile 1 ----
    {
        unsigned int xpk[16], xsh[16];
        const float4* xr = (const float4*)(x + (rowbase + 32 + rl) * 32);
        #pragma unroll
        for (int c = 0; c < 8; ++c) {
            float4 v = xr[c];
            xpk[2 * c + 0] = pk2_f16(v.x, v.y);
            xpk[2 * c + 1] = pk2_f16(v.z, v.w);
        }
        #pragma unroll
        for (int c = 0; c < 16; ++c)
            xsh[c] = __builtin_amdgcn_perm(xpk[(c + 1) & 15], xpk[c], 0x05040302u);
        #pragma unroll
        for (int c = 0; c < 16; ++c) {
            ypk1[c] = hi ? xpk[(c + 4) & 15] : xpk[c];
            ysh1[c] = hi ? xsh[(c + 4) & 15] : xsh[c];
        }
    }

    f32x16 accA, accB;
    #pragma unroll
    for (int e = 0; e < 16; ++e) { accA[e] = 0.0f; accB[e] = 0.0f; }

    __syncthreads();

    // ---- K loop: 33 steps (17 diagonals), fully unrolled, SSA-pure ----
    #pragma unroll
    for (int s = 0; s < 33; ++s) {
        const int d   = (s == 32) ? 16 : (s >> 1);
        const int q8  = ((s == 32) ? 0 : (s & 1)) * 8;
        const int dh  = d >> 1;
        const bool od = (d & 1) != 0;
        f16x8 bfrag = *(const f16x8*)(&btab[(s * 64 + lane) * 8]);

        {   // tile 0
            f16x2 a0 = u2h(ypk0[q8 + 0]) * u2h(od ? ysh0[(q8 + 0 + dh) & 15] : ypk0[(q8 + 0 + dh) & 15]);
            f16x2 a1 = u2h(ypk0[q8 + 1]) * u2h(od ? ysh0[(q8 + 1 + dh) & 15] : ypk0[(q8 + 1 + dh) & 15]);
            f16x2 a2 = u2h(ypk0[q8 + 2]) * u2h(od ? ysh0[(q8 + 2 + dh) & 15] : ypk0[(q8 + 2 + dh) & 15]);
            f16x2 a3 = u2h(ypk0[q8 + 3]) * u2h(od ? ysh0[(q8 + 3 + dh) & 15] : ypk0[(q8 + 3 + dh) & 15]);
            f16x4 lo = __builtin_shufflevector(a0, a1, 0, 1, 2, 3);
            f16x4 hf = __builtin_shufflevector(a2, a3, 0, 1, 2, 3);
            f16x8 a  = __builtin_shufflevector(lo, hf, 0, 1, 2, 3, 4, 5, 6, 7);
            accA = __builtin_amdgcn_mfma_f32_32x32x16_f16(a, bfrag, accA, 0, 0, 0);
        }
        {   // tile 1
            f16x2 a0 = u2h(ypk1[q8 + 0]) * u2h(od ? ysh1[(q8 + 0 + dh) & 15] : ypk1[(q8 + 0 + dh) & 15]);
            f16x2 a1 = u2h(ypk1[q8 + 1]) * u2h(od ? ysh1[(q8 + 1 + dh) & 15] : ypk1[(q8 + 1 + dh) & 15]);
            f16x2 a2 = u2h(ypk1[q8 + 2]) * u2h(od ? ysh1[(q8 + 2 + dh) & 15] : ypk1[(q8 + 2 + dh) & 15]);
            f16x2 a3 = u2h(ypk1[q8 + 3]) * u2h(od ? ysh1[(q8 + 3 + dh) & 15] : ypk1[(q8 + 3 + dh) & 15]);
            f16x4 lo = __builtin_shufflevector(a0, a1, 0, 1, 2, 3);
            f16x4 hf = __builtin_shufflevector(a2, a3, 0, 1, 2, 3);
            f16x8 a  = __builtin_shufflevector(lo, hf, 0, 1, 2, 3, 4, 5, 6, 7);
            accB = __builtin_amdgcn_mfma_f32_32x32x16_f16(a, bfrag, accB, 0, 0, 0);
        }
    }

    // ---- store: col = lane&31 (k), row = (e&3) + 8*(e>>2) + 4*hi ----
    #pragma unroll
    for (int e = 0; e < 16; ++e) {
        int row = (e & 3) + 8 * (e >> 2) + 4 * hi;
        out[(rowbase + row) * 32 + rl]      = accA[e];
        out[(rowbase + 32 + row) * 32 + rl] = accB[e];
    }
}

extern "C" void kernel_launch(void* const* d_in, const int* in_sizes, int n_in,
                              void* d_out, int out_size, void* d_ws, size_t ws_size,
                              hipStream_t stream) {
    const float* x = (const float*)d_in[0];
    const float* W = (const float*)d_in[1];
    float* out = (float*)d_out;
    int nrows = in_sizes[0] / 32;          // 262144
    int grid  = nrows / 512;               // 512 blocks x 512 thr
    quadform_kernel<<<grid, 512, 0, stream>>>(x, W, out);
}

// Round 12
// 30.101 us; speedup vs baseline: 2.6838x; 2.6838x over previous
//
#include <hip/hip_runtime.h>

// out[n,k] = sum_{i,j} x[n,i] * W[k,i,j] * x[n,j]   (N=262144 rows, D=32)
// R12 = R11's symmetrized GEMM (K 1024 -> 528 = 33 MFMA steps, math verified
// absmax 0.25) with R11's two regressions fixed:
//  1) btab gather moved to a ONE-TIME prep kernel -> d_ws (was: per-block
//     scattered gather, ~17M uncoalesced 4B requests, ~28us). Main kernel
//     copies the 33KiB table to LDS with coalesced uint4 loads.
//  2) ysh[] eliminated (-32 regs): odd-diagonal shifted pair computed
//     in-loop as one v_perm of two static ypk regs. Persistent state =
//     ypk 32 + acc 32(AGPR) -> no spill; launch_bounds(512,2) (R11's
//     (512,4) + 96 live regs forced VGPR=60 + spill).
// Diagonal form: p = d*32+i, z_p = x_i * x_{(i+d)&31}, d=0..16;
// Wf[p,k] = W[k,i,j]+W[k,j,i] (d=0 diag; d=16 i<16 only). Each unordered
// pair exactly once. A-slot (hi,b) of step s(q,d): m = q*16+hi*8+b,
// value = x_m * x_{(m+d)&31}; pair t: ypk[q8+t] * rot(ypk)[(q8+t+dh)&15],
// ypk pre-rotated by hi*4 so all indices are compile-time.

typedef _Float16 f16x2 __attribute__((ext_vector_type(2)));
typedef _Float16 f16x4 __attribute__((ext_vector_type(4)));
typedef _Float16 f16x8 __attribute__((ext_vector_type(8)));
typedef float    f32x16 __attribute__((ext_vector_type(16)));

static __device__ __forceinline__ unsigned int pk2_f16(float lo, float hi) {
    return __builtin_bit_cast(unsigned int, __builtin_amdgcn_cvt_pkrtz(lo, hi));
}
static __device__ __forceinline__ f16x2 u2h(unsigned int u) {
    return __builtin_bit_cast(f16x2, u);
}
static __device__ __forceinline__ unsigned short f16b(float f) {
    _Float16 h = (_Float16)f;
    return __builtin_bit_cast(unsigned short, h);
}

// ---- one-time prep: symmetrized fragment table (16896 f16 = 33 KiB) ----
// bt[(n*64+l)*8+b] = f16( W[k,i,j]+W[k,j,i] ),  k=l&31, i=q*16+(l>>5)*8+b,
// j=(i+d)&31, d=(n==32)?16:n>>1, q=(n==32)?0:n&1;  d==0 -> W[k,i,i].
__global__ __launch_bounds__(512)
void prep_btab_sym(const float* __restrict__ W, unsigned short* __restrict__ bt) {
    int idx = blockIdx.x * 512 + threadIdx.x;   // 0..16895 (grid = 33)
    int n = idx >> 9;
    int e = idx & 511;
    int l = e >> 3, b = e & 7;
    int d = (n == 32) ? 16 : (n >> 1);
    int q = (n == 32) ? 0  : (n & 1);
    int i = q * 16 + ((l >> 5) << 3) + b;
    int j = (i + d) & 31;
    const float* Wk = W + (l & 31) * 1024;
    float v = (d == 0) ? Wk[i * 32 + i] : Wk[i * 32 + j] + Wk[j * 32 + i];
    bt[idx] = f16b(v);
}

__global__ __launch_bounds__(512, 2)
void quadform_kernel(const float* __restrict__ x,
                     const unsigned short* __restrict__ bt_ws,
                     float* __restrict__ out) {
    __shared__ __align__(16) unsigned short btab[33 * 64 * 8];   // 33 KiB

    const int tid  = threadIdx.x;
    const int lane = tid & 63;
    const int wave = tid >> 6;
    const int hi   = lane >> 5;
    const int rl   = lane & 31;
    const long rowbase = (long)blockIdx.x * 512 + wave * 64;

    // ---- x loads issued first (latency hides under the btab copy) ----
    const float4* xr0 = (const float4*)(x + (rowbase + rl) * 32);
    const float4* xr1 = (const float4*)(x + (rowbase + 32 + rl) * 32);

    // ---- coalesced copy ws -> LDS (2112 uint4) ----
    {
        const uint4* src = (const uint4*)bt_ws;
        uint4* dst = (uint4*)btab;
        #pragma unroll
        for (int c = 0; c < 5; ++c) {
            int idx = c * 512 + tid;
            if (idx < 2112) dst[idx] = src[idx];
        }
    }

    // ---- pack rows to f16 pairs, pre-rotate by hi*4 (static indices) ----
    unsigned int ypk0[16], ypk1[16];
    {
        unsigned int xpk0[16], xpk1[16];
        #pragma unroll
        for (int c = 0; c < 8; ++c) {
            float4 v0 = xr0[c];
            float4 v1 = xr1[c];
            xpk0[2 * c + 0] = pk2_f16(v0.x, v0.y);
            xpk0[2 * c + 1] = pk2_f16(v0.z, v0.w);
            xpk1[2 * c + 0] = pk2_f16(v1.x, v1.y);
            xpk1[2 * c + 1] = pk2_f16(v1.z, v1.w);
        }
        #pragma unroll
        for (int c = 0; c < 16; ++c) {
            ypk0[c] = hi ? xpk0[(c + 4) & 15] : xpk0[c];
            ypk1[c] = hi ? xpk1[(c + 4) & 15] : xpk1[c];
        }
    }

    f32x16 accA, accB;
    #pragma unroll
    for (int e = 0; e < 16; ++e) { accA[e] = 0.0f; accB[e] = 0.0f; }

    __syncthreads();

    // ---- K loop: 33 steps (17 circular diagonals), fully unrolled, SSA ----
    #pragma unroll
    for (int s = 0; s < 33; ++s) {
        const int d   = (s == 32) ? 16 : (s >> 1);
        const int q8  = ((s == 32) ? 0 : (s & 1)) * 8;
        const int dh  = d >> 1;
        const bool od = (d & 1) != 0;
        f16x8 bfrag = *(const f16x8*)(&btab[(s * 64 + lane) * 8]);

        {   // tile 0
            f16x2 b0 = od ? u2h(__builtin_amdgcn_perm(ypk0[(q8 + 0 + dh + 1) & 15], ypk0[(q8 + 0 + dh) & 15], 0x05040302u)) : u2h(ypk0[(q8 + 0 + dh) & 15]);
            f16x2 b1 = od ? u2h(__builtin_amdgcn_perm(ypk0[(q8 + 1 + dh + 1) & 15], ypk0[(q8 + 1 + dh) & 15], 0x05040302u)) : u2h(ypk0[(q8 + 1 + dh) & 15]);
            f16x2 b2 = od ? u2h(__builtin_amdgcn_perm(ypk0[(q8 + 2 + dh + 1) & 15], ypk0[(q8 + 2 + dh) & 15], 0x05040302u)) : u2h(ypk0[(q8 + 2 + dh) & 15]);
            f16x2 b3 = od ? u2h(__builtin_amdgcn_perm(ypk0[(q8 + 3 + dh + 1) & 15], ypk0[(q8 + 3 + dh) & 15], 0x05040302u)) : u2h(ypk0[(q8 + 3 + dh) & 15]);
            f16x2 a0 = u2h(ypk0[q8 + 0]) * b0;
            f16x2 a1 = u2h(ypk0[q8 + 1]) * b1;
            f16x2 a2 = u2h(ypk0[q8 + 2]) * b2;
            f16x2 a3 = u2h(ypk0[q8 + 3]) * b3;
            f16x4 lo = __builtin_shufflevector(a0, a1, 0, 1, 2, 3);
            f16x4 hf = __builtin_shufflevector(a2, a3, 0, 1, 2, 3);
            f16x8 a  = __builtin_shufflevector(lo, hf, 0, 1, 2, 3, 4, 5, 6, 7);
            accA = __builtin_amdgcn_mfma_f32_32x32x16_f16(a, bfrag, accA, 0, 0, 0);
        }
        {   // tile 1
            f16x2 b0 = od ? u2h(__builtin_amdgcn_perm(ypk1[(q8 + 0 + dh + 1) & 15], ypk1[(q8 + 0 + dh) & 15], 0x05040302u)) : u2h(ypk1[(q8 + 0 + dh) & 15]);
            f16x2 b1 = od ? u2h(__builtin_amdgcn_perm(ypk1[(q8 + 1 + dh + 1) & 15], ypk1[(q8 + 1 + dh) & 15], 0x05040302u)) : u2h(ypk1[(q8 + 1 + dh) & 15]);
            f16x2 b2 = od ? u2h(__builtin_amdgcn_perm(ypk1[(q8 + 2 + dh + 1) & 15], ypk1[(q8 + 2 + dh) & 15], 0x05040302u)) : u2h(ypk1[(q8 + 2 + dh) & 15]);
            f16x2 b3 = od ? u2h(__builtin_amdgcn_perm(ypk1[(q8 + 3 + dh + 1) & 15], ypk1[(q8 + 3 + dh) & 15], 0x05040302u)) : u2h(ypk1[(q8 + 3 + dh) & 15]);
            f16x2 a0 = u2h(ypk1[q8 + 0]) * b0;
            f16x2 a1 = u2h(ypk1[q8 + 1]) * b1;
            f16x2 a2 = u2h(ypk1[q8 + 2]) * b2;
            f16x2 a3 = u2h(ypk1[q8 + 3]) * b3;
            f16x4 lo = __builtin_shufflevector(a0, a1, 0, 1, 2, 3);
            f16x4 hf = __builtin_shufflevector(a2, a3, 0, 1, 2, 3);
            f16x8 a  = __builtin_shufflevector(lo, hf, 0, 1, 2, 3, 4, 5, 6, 7);
            accB = __builtin_amdgcn_mfma_f32_32x32x16_f16(a, bfrag, accB, 0, 0, 0);
        }
    }

    // ---- store: col = lane&31 (k), row = (e&3) + 8*(e>>2) + 4*hi ----
    #pragma unroll
    for (int e = 0; e < 16; ++e) {
        int row = (e & 3) + 8 * (e >> 2) + 4 * hi;
        out[(rowbase + row) * 32 + rl]      = accA[e];
        out[(rowbase + 32 + row) * 32 + rl] = accB[e];
    }
}

extern "C" void kernel_launch(void* const* d_in, const int* in_sizes, int n_in,
                              void* d_out, int out_size, void* d_ws, size_t ws_size,
                              hipStream_t stream) {
    const float* x = (const float*)d_in[0];
    const float* W = (const float*)d_in[1];
    float* out = (float*)d_out;
    unsigned short* bt = (unsigned short*)d_ws;    // 33 KiB table

    prep_btab_sym<<<33, 512, 0, stream>>>(W, bt);
    int nrows = in_sizes[0] / 32;          // 262144
    int grid  = nrows / 512;               // 512 blocks x 512 thr
    quadform_kernel<<<grid, 512, 0, stream>>>(x, bt, out);
}